// Round 15
// baseline (198.480 us; speedup 1.0000x reference)
//
#include <hip/hip_runtime.h>
#include <stdint.h>
#include <stddef.h>

// B=4, L=2048, E=1024, H=16, HD=64, BH=64 heads. f32 inputs/outputs.
// score = (q.k/8 + 0.1) * exp(-10*gauss[bh>>1][m]); softmax over m; @v; out-proj.
// Round 15: fused f32->bf16 in-proj moved onto the FAST GEMM skeleton
// (r7: 128x128 tile, BK=32, 3 LDS buffers, 2-barrier, 8 waves, 2 blocks/CU).
// A staged f32 via global_load_lds (24KB/buffer total with B), converted at
// fragment load (2x ds_read_b128 + v_cvt_pk). Out-proj keeps r11 8-phase bf16.

typedef __attribute__((ext_vector_type(8))) short bf16x8;
typedef __attribute__((ext_vector_type(4))) float f32x4;

__device__ __forceinline__ unsigned short f2b(float f) {
  unsigned int u = __builtin_bit_cast(unsigned int, f);
  u += 0x7FFFu + ((u >> 16) & 1u);
  return (unsigned short)(u >> 16);
}
__device__ __forceinline__ bf16x8 cvt8(f32x4 a, f32x4 b) {
  bf16x8 r;
#pragma unroll
  for (int i = 0; i < 4; ++i) { r[i] = (short)f2b(a[i]); r[4 + i] = (short)f2b(b[i]); }
  return r;
}
// packed RNE f32->bf16 via HW instruction (T12): 4 instr per 8 values
__device__ __forceinline__ bf16x8 pk8(f32x4 a, f32x4 b) {
  union { bf16x8 v; unsigned int w[4]; } u;
  asm("v_cvt_pk_bf16_f32 %0, %1, %2" : "=v"(u.w[0]) : "v"(a[0]), "v"(a[1]));
  asm("v_cvt_pk_bf16_f32 %0, %1, %2" : "=v"(u.w[1]) : "v"(a[2]), "v"(a[3]));
  asm("v_cvt_pk_bf16_f32 %0, %1, %2" : "=v"(u.w[2]) : "v"(b[0]), "v"(b[1]));
  asm("v_cvt_pk_bf16_f32 %0, %1, %2" : "=v"(u.w[3]) : "v"(b[2]), "v"(b[3]));
  return u.v;
}
__device__ __forceinline__ float fexp2(float x) { return __builtin_amdgcn_exp2f(x); }

#define GLD16(gp, lp) __builtin_amdgcn_global_load_lds( \
  (const __attribute__((address_space(1))) void*)(gp), \
  (__attribute__((address_space(3))) void*)(lp), 16, 0, 0)

// ---------------- prep: gtab = exp(-10*gauss)*log2e, btab = 0.1*gtab ----------------
__global__ void __launch_bounds__(256) gw_exp_kernel(const float* __restrict__ g,
                                                     float* __restrict__ gtab,
                                                     float* __restrict__ btab, int n) {
  int i = blockIdx.x * 256 + threadIdx.x;
  if (i < n) {
    const float e = __expf(g[i] * -10.0f) * 1.44269504f;
    gtab[i] = e;
    btab[i] = 0.1f * e;
  }
}

// ---------------- prep: f32 -> bf16 conversion of WEIGHTS only ----------------
// dst layout (1Mi-elem segments): ipw [0, 3M) | opw [3M, 4M)
__global__ void __launch_bounds__(256) conv_bf16_kernel(
    const float* __restrict__ w1, const float* __restrict__ w2,
    unsigned short* __restrict__ dst)
{
  const size_t i = ((size_t)blockIdx.x * 256 + threadIdx.x) * 8;   // 8 elems/thread
  const float* s; size_t off;
  if (i < ((size_t)3 << 20)) { s = w1; off = i; }
  else                       { s = w2; off = i - ((size_t)3 << 20); }
  const f32x4 a = *(const f32x4*)(s + off);
  const f32x4 b = *(const f32x4*)(s + off + 4);
  *(bf16x8*)(dst + i) = cvt8(a, b);
}

// ------ in-projection GEMM: C = A(f32) @ B(bf16)^T, 128x128 tile, 8 waves ------
// r7 skeleton: BK=32, 3 LDS buffers x 24KB {A f32 16KB | B bf16 8KB},
// 2 blocks/CU. 3 GLD16/thread/tile; steady vmcnt(3) (tile kt landed, kt+1 in
// flight); raw barrier. Race ledger (r7-verified shape): window touches
// read-buf kt%3 and write-buf (kt+2)%3 only; vmcnt(3) at bar(kt) leaves only
// tile-(kt+1)'s loads outstanding.
// A rows 128B (32 f32, 8 chunks); LDS[r][c] = global chunk c^(r&7).
// B rows 64B (32 bf16, 4 chunks);  LDS[r][c] = global chunk c^((r>>1)&3).
// A fragment: 2x ds_read_b128 (f32) + pk8 -> bf16 (2-way bank = free).
// Wave (w>>2, w&3) owns 64x32: acc[4][2].
// Epilogue (r7-verified): tn<8 q (*0.125), tn<16 k (*gtab), tn>=16 v via LDS
// transpose -> coalesced Vt rows.
__global__ void __launch_bounds__(512, 4) gemm_ip(
    const float* __restrict__ Aq, const float* __restrict__ Ak,
    const float* __restrict__ Av, const unsigned short* __restrict__ Bw,
    const float* __restrict__ bias, const float* __restrict__ gtab,
    unsigned short* __restrict__ Qo, unsigned short* __restrict__ Ko,
    unsigned short* __restrict__ Vto, int K, int nTN)
{
  const int nwg = gridDim.x;
  const int cpx = nwg >> 3;                                     // nwg % 8 == 0
  const int bid2 = (blockIdx.x & 7) * cpx + (blockIdx.x >> 3);  // XCD swizzle
  const int tm = bid2 / nTN, tn = bid2 % nTN;   // 128-row x 128-col tiles

  __shared__ __align__(16) char lds[3][24576];  // [buf]: A f32 [0,16K) | B [16K,24K)

  const int tid = threadIdx.x;
  const int w = tid >> 6, l = tid & 63;          // 8 waves
  const int lr = l & 15, lg = l >> 4;
  const size_t Kz = (size_t)K;

  const float* Af = tn < 8 ? Aq : (tn < 16 ? Ak : Av);

  // staging: A = 2 units/thread (1024 x 16B), B = 1 unit/thread (512 x 16B)
  auto stage = [&](int buf, int kt) {
    const int k0 = kt * 32;
#pragma unroll
    for (int j = 0; j < 2; ++j) {
      const int u = j * 512 + tid;
      const int rr = u >> 3;                     // A row
      const int ce = ((u & 7) ^ (rr & 7)) << 2;  // f32 elem offset (swizzled)
      GLD16(Af + (size_t)(tm * 128 + rr) * Kz + k0 + ce, &lds[buf][u * 16]);
    }
    const int rb = tid >> 2;                     // B row
    const int cb = ((tid & 3) ^ ((rb >> 1) & 3)) << 3;  // bf16 elem offset
    GLD16(Bw + (size_t)(tn * 128 + rb) * Kz + k0 + cb, &lds[buf][16384 + tid * 16]);
  };

  f32x4 acc[4][2];
  const f32x4 zero = {0.f, 0.f, 0.f, 0.f};
#pragma unroll
  for (int i = 0; i < 4; ++i)
#pragma unroll
    for (int j = 0; j < 2; ++j) acc[i][j] = zero;

  const int wr = (w >> 2) * 64, wc = (w & 3) * 32;
  const int NT = K / 32;

  stage(0, 0);
  stage(1, 1);
  int rbuf = 0, wbuf = 2;
  for (int kt = 0; kt < NT; ++kt) {
    if (kt == NT - 1) { asm volatile("s_waitcnt vmcnt(0)" ::: "memory"); }
    else              { asm volatile("s_waitcnt vmcnt(3)" ::: "memory"); }
    __builtin_amdgcn_sched_barrier(0);
    __builtin_amdgcn_s_barrier();
    __builtin_amdgcn_sched_barrier(0);
    if (kt + 2 < NT) stage(wbuf, kt + 2);
    const char* la = lds[rbuf];
    const char* lb = lds[rbuf] + 16384;
    bf16x8 af[4], bfr[2];
#pragma unroll
    for (int mi = 0; mi < 4; ++mi) {
      const int ra = wr + mi * 16 + lr;
      const f32x4 lo = *(const f32x4*)(la + ra * 128 + ((((lg << 1))     ^ (ra & 7)) << 4));
      const f32x4 hi = *(const f32x4*)(la + ra * 128 + ((((lg << 1) | 1) ^ (ra & 7)) << 4));
      af[mi] = pk8(lo, hi);
    }
#pragma unroll
    for (int ni = 0; ni < 2; ++ni) {
      const int rb2 = wc + ni * 16 + lr;
      bfr[ni] = *(const bf16x8*)(lb + rb2 * 64 + ((lg ^ ((rb2 >> 1) & 3)) << 4));
    }
#pragma unroll
    for (int mi = 0; mi < 4; ++mi)
#pragma unroll
      for (int ni = 0; ni < 2; ++ni)
        acc[mi][ni] = __builtin_amdgcn_mfma_f32_16x16x32_bf16(
            af[mi], bfr[ni], acc[mi][ni], 0, 0, 0);
    rbuf = (rbuf == 2) ? 0 : rbuf + 1;
    wbuf = (wbuf == 2) ? 0 : wbuf + 1;
  }

  // ---------------- epilogue (r7-verified, + gtab K-scaling) ----------------
  if (tn >= 16) {
    // V: transpose through LDS -> coalesced Vt rows.
    __syncthreads();                              // staging LDS now dead
    char* T = &lds[0][0];                         // [128 cnl][256B], XOR-swizzled
#pragma unroll
    for (int ni = 0; ni < 2; ++ni) {
      const int cnl = wc + ni * 16 + lr;
      const float bv = bias[tn * 128 + cnl];
#pragma unroll
      for (int mi = 0; mi < 4; ++mi)
#pragma unroll
        for (int r = 0; r < 4; ++r) {
          const int rml = wr + mi * 16 + lg * 4 + r;
          const int byte = cnl * 256 + (((rml * 2)) ^ ((cnl & 3) << 5));
          *(unsigned short*)(T + byte) = f2b(acc[mi][ni][r] + bv);
        }
    }
    __syncthreads();
    const int bbase = (tm >> 4) * 16 + (tn - 16) * 2;  // bh = bbase + (cnl>>6)
    const size_t ncol = (size_t)(tm & 15) * 128;
#pragma unroll
    for (int rep = 0; rep < 4; ++rep) {
      const int U = rep * 512 + tid;              // 2048 units of 16B
      const int row = U >> 4;                     // cnl
      const int un = U & 15;                      // 16B unit within row
      const bf16x8 vv = *(const bf16x8*)(T + row * 256 + ((un * 16) ^ ((row & 3) << 5)));
      const int bh = bbase + (row >> 6);
      const int d = row & 63;
      *(bf16x8*)(Vto + ((size_t)bh * 64 + d) * 2048 + ncol + un * 8) = vv;
    }
  } else {
    // q (tn<8) and k (tn<16, scaled by gtab): direct stores.
#pragma unroll
    for (int ni = 0; ni < 2; ++ni) {
      const int cn = tn * 128 + wc + ni * 16 + lr;
      const float bv = bias[cn];
      const int j = cn & 1023;
      const float* gK = nullptr;
      if (tn >= 8) {                              // K-block: per-pair g row
        const int bh_ = (tm >> 4) * 16 + (j >> 6);
        gK = gtab + (size_t)(bh_ >> 1) * 2048;
      }
#pragma unroll
      for (int mi = 0; mi < 4; ++mi) {
        const int rm0 = tm * 128 + wr + mi * 16 + lg * 4;
        f32x4 g4;
        if (gK) g4 = *(const f32x4*)&gK[rm0 & 2047];
#pragma unroll
        for (int r = 0; r < 4; ++r) {
          const int rm = rm0 + r;
          const float val = acc[mi][ni][r] + bv;
          const int bh = (rm >> 11) * 16 + (j >> 6);
          const int d = j & 63;
          const int nr = rm & 2047;
          if (tn < 8) Qo[((size_t)bh * 2048 + nr) * 64 + d] = f2b(val * 0.125f);
          else        Ko[((size_t)bh * 2048 + nr) * 64 + d] = f2b(val * g4[r]);
        }
      }
    }
  }
}

// ------- out-proj GEMM: C = A(bf16) @ B(bf16)^T + bias -> f32, 8-phase -------
// (r11 EPI==1 path, verified: 128x256 tile, BK=64, 2 slots x 48KB, counted
// vmcnt(4) at slot-opens, never 0 in-loop.)
__global__ void __launch_bounds__(512, 2) gemm_op(
    const unsigned short* __restrict__ Abf, const unsigned short* __restrict__ Bw,
    const float* __restrict__ bias, float* __restrict__ Co, int N, int K, int nTN)
{
  const int nwg = gridDim.x;
  const int cpx = nwg >> 3;
  const int bid2 = (blockIdx.x & 7) * cpx + (blockIdx.x >> 3);  // XCD swizzle
  const int tm = bid2 / nTN, tn = bid2 % nTN;

  __shared__ __align__(16) char lds[2][49152];

  const int tid = threadIdx.x;
  const int w = tid >> 6, l = tid & 63;
  const int lr = l & 15, lg = l >> 4;
  const int wm = w >> 2, wn = w & 3;
  const size_t Kz = (size_t)K;

  const int r0 = tid >> 3;
  const int e0 = (((tid & 7) ^ ((tid >> 3) & 7)) << 3);
  const size_t arow0 = (size_t)(tm * 128 + r0);
  const size_t brow0 = (size_t)(tn * 256 + r0);

  auto stA = [&](int s, int k0) {
    GLD16(Abf + arow0 * Kz + k0 + e0,        &lds[s][tid * 16]);
    GLD16(Abf + (arow0 + 64) * Kz + k0 + e0, &lds[s][8192 + tid * 16]);
  };
  auto stB = [&](int s, int h, int k0) {
    const size_t rb = brow0 + h * 128;
    GLD16(Bw + rb * Kz + k0 + e0,        &lds[s][16384 + h * 16384 + tid * 16]);
    GLD16(Bw + (rb + 64) * Kz + k0 + e0, &lds[s][16384 + h * 16384 + 8192 + tid * 16]);
  };

  int offA[4][2], offB[4][2];
#pragma unroll
  for (int m = 0; m < 4; ++m) {
    const int ra = wm * 64 + m * 16 + lr;
#pragma unroll
    for (int kk = 0; kk < 2; ++kk)
      offA[m][kk] = ra * 128 + ((((kk << 2) | lg) ^ (ra & 7)) << 4);
  }
#pragma unroll
  for (int n = 0; n < 4; ++n) {
    const int br = wn * 64 + n * 16 + lr;
    const int lrow = br & 127;
#pragma unroll
    for (int kk = 0; kk < 2; ++kk)
      offB[n][kk] = 16384 + (br >> 7) * 16384 + lrow * 128 +
                    ((((kk << 2) | lg) ^ (lrow & 7)) << 4);
  }

  f32x4 acc[4][4];
  const f32x4 zero = {0.f, 0.f, 0.f, 0.f};
#pragma unroll
  for (int i = 0; i < 4; ++i)
#pragma unroll
    for (int j = 0; j < 4; ++j) acc[i][j] = zero;

  bf16x8 af[2][2], bf[4][2];

  auto loadA = [&](const char* Ls, int mh) {
#pragma unroll
    for (int mm = 0; mm < 2; ++mm)
#pragma unroll
      for (int kk = 0; kk < 2; ++kk)
        af[mm][kk] = *(const bf16x8*)(Ls + offA[mh * 2 + mm][kk]);
  };
  auto loadB = [&](const char* Ls) {
#pragma unroll
    for (int n = 0; n < 4; ++n)
#pragma unroll
      for (int kk = 0; kk < 2; ++kk)
        bf[n][kk] = *(const bf16x8*)(Ls + offB[n][kk]);
  };
  auto mfmaq = [&](int mh) {
    asm volatile("s_waitcnt lgkmcnt(0)" ::: "memory");
    __builtin_amdgcn_sched_barrier(0);
    __builtin_amdgcn_s_setprio(1);
#pragma unroll
    for (int mm = 0; mm < 2; ++mm)
#pragma unroll
      for (int n = 0; n < 4; ++n) {
        f32x4 a = acc[mh * 2 + mm][n];
        a = __builtin_amdgcn_mfma_f32_16x16x32_bf16(af[mm][0], bf[n][0], a, 0, 0, 0);
        a = __builtin_amdgcn_mfma_f32_16x16x32_bf16(af[mm][1], bf[n][1], a, 0, 0, 0);
        acc[mh * 2 + mm][n] = a;
      }
    __builtin_amdgcn_s_setprio(0);
  };

#define FBAR() do { \
  asm volatile("" ::: "memory"); \
  __builtin_amdgcn_sched_barrier(0); \
  __builtin_amdgcn_s_barrier(); \
  __builtin_amdgcn_sched_barrier(0); \
  asm volatile("" ::: "memory"); \
} while (0)

  const char* L0 = (const char*)lds[0];
  const char* L1 = (const char*)lds[1];
  const int NI = K / 128;

  stA(0, 0); stB(0, 0, 0); stB(0, 1, 0);

  for (int i = 0; i < NI; ++i) {
    const int k1 = i * 128 + 64;
    const int k2 = i * 128 + 128;
    stA(1, k1); stB(1, 0, k1);
    asm volatile("s_waitcnt vmcnt(4)" ::: "memory");
    FBAR();
    loadA(L0, 0); loadB(L0);
    mfmaq(0);
    FBAR();
    stB(1, 1, k1);
    loadA(L0, 1);
    mfmaq(1);
    FBAR();
    if (i + 1 < NI) {
      stA(0, k2); stB(0, 0, k2);
      asm volatile("s_waitcnt vmcnt(4)" ::: "memory");
    } else {
      asm volatile("s_waitcnt vmcnt(0)" ::: "memory");
    }
    FBAR();
    loadA(L1, 0); loadB(L1);
    mfmaq(0);
    FBAR();
    if (i + 1 < NI) stB(0, 1, k2);
    loadA(L1, 1);
    mfmaq(1);
    FBAR();
  }

#pragma unroll
  for (int n = 0; n < 4; ++n) {
    const int cn = tn * 256 + wn * 64 + n * 16 + lr;
    const float bv = bias[cn];
#pragma unroll
    for (int m = 0; m < 4; ++m) {
#pragma unroll
      for (int r = 0; r < 4; ++r) {
        const int rm = tm * 128 + wm * 64 + m * 16 + lg * 4 + r;
        Co[(size_t)rm * N + cn] = acc[m][n][r] + bv;
      }
    }
  }
}

// ---------------- flash attention: 4 waves x 64 q-rows, 64-key tiles ----------------
// (unchanged from round 9 — verified)
__global__ void __launch_bounds__(256, 2) attn_kernel(
    const unsigned short* __restrict__ Q, const unsigned short* __restrict__ Kf,
    const unsigned short* __restrict__ Vt, const float* __restrict__ btab,
    unsigned short* __restrict__ O)
{
  const int bid2 = (blockIdx.x & 7) * 64 + (blockIdx.x >> 3);  // grid = 512 = 8*64
  const int bh = bid2 >> 3;
  const int qb = bid2 & 7;
  const int tid = threadIdx.x;
  const int w = tid >> 6, l = tid & 63;
  const int lr = l & 15, lg = l >> 4;

  __shared__ __align__(16) unsigned short Kl[2][64 * 64];
  __shared__ __align__(16) unsigned short Vl[2][64 * 64];

  const int qrow = qb * 256 + w * 64 + lr;
  const unsigned short* qp = &Q[((size_t)bh * 2048 + qrow) * 64];
  bf16x8 aq[4][2];
#pragma unroll
  for (int st = 0; st < 4; ++st) {
    aq[st][0] = *(const bf16x8*)&qp[st * 16 * 64 + lg * 8];
    aq[st][1] = *(const bf16x8*)&qp[st * 16 * 64 + 32 + lg * 8];
  }

  const f32x4 zero = {0.f, 0.f, 0.f, 0.f};
  f32x4 accO[4][4];                               // [st][dt]
  f32x4 lsum[4];
#pragma unroll
  for (int st = 0; st < 4; ++st) {
    lsum[st] = zero;
#pragma unroll
    for (int dt = 0; dt < 4; ++dt) accO[st][dt] = zero;
  }

  const short oneb = (short)0x3F80;               // bf16 1.0
  const bf16x8 vones = {oneb, oneb, oneb, oneb, oneb, oneb, oneb, oneb};

  int off[4][2];
#pragma unroll
  for (int mt = 0; mt < 4; ++mt)
#pragma unroll
    for (int c = 0; c < 2; ++c) {
      const int rr = mt * 16 + lr;
      off[mt][c] = rr * 128 + ((((c << 2) + lg) ^ (rr & 7)) << 4);
    }

  const int rr0 = w * 8 + (l >> 3);
  const int cc = ((l & 7) ^ (rr0 & 7)) * 8;
  const int kk0 = (rr0 & 35) | ((rr0 & 12) << 1) | ((rr0 & 16) >> 2);
  const unsigned short* kSrc = &Kf[((size_t)bh * 2048 + kk0) * 64 + cc];
  const unsigned short* vSrc = &Vt[((size_t)bh * 64 + rr0) * 2048 + cc];

  auto stageKV = [&](int buf) {
    GLD16(kSrc,             &Kl[buf][w * 512]);
    GLD16(kSrc + 32 * 64,   &Kl[buf][(w + 4) * 512]);
    GLD16(vSrc,             &Vl[buf][w * 512]);
    GLD16(vSrc + 32 * 2048, &Vl[buf][(w + 4) * 512]);
    kSrc += 64 * 64;
    vSrc += 64;
  };

  const float* brow = &btab[(size_t)(bh >> 1) * 2048];

  stageKV(0);
  for (int t = 0; t < 32; ++t) {
    __syncthreads();
    if (t + 1 < 32) stageKV((t + 1) & 1);
    const char* kl = (const char*)Kl[t & 1];
    const char* vl = (const char*)Vl[t & 1];

    bf16x8 ap[4][2];
#pragma unroll
    for (int half = 0; half < 2; ++half) {
      f32x4 s[4][2];
      __builtin_amdgcn_s_setprio(1);
#pragma unroll
      for (int mh = 0; mh < 2; ++mh) {
        const int mt = half * 2 + mh;
        const bf16x8 bk0 = *(const bf16x8*)(kl + off[mt][0]);
        const bf16x8 bk1 = *(const bf16x8*)(kl + off[mt][1]);
        const f32x4 b4 = *(const f32x4*)&brow[t * 64 + (half << 5) + (lg << 3) + (mh << 2)];
#pragma unroll
        for (int st = 0; st < 4; ++st) {
          f32x4 a = __builtin_amdgcn_mfma_f32_16x16x32_bf16(bk0, aq[st][0], b4, 0, 0, 0);
          a = __builtin_amdgcn_mfma_f32_16x16x32_bf16(bk1, aq[st][1], a, 0, 0, 0);
          s[st][mh] = a;
        }
      }
      __builtin_amdgcn_s_setprio(0);
#pragma unroll
      for (int st = 0; st < 4; ++st) {
#pragma unroll
        for (int mh = 0; mh < 2; ++mh)
#pragma unroll
          for (int r = 0; r < 4; ++r) s[st][mh][r] = fexp2(s[st][mh][r]);
        ap[st][half] = pk8(s[st][0], s[st][1]);
      }
    }

    __builtin_amdgcn_s_setprio(1);
#pragma unroll
    for (int st = 0; st < 4; ++st) {
      lsum[st] = __builtin_amdgcn_mfma_f32_16x16x32_bf16(ap[st][0], vones, lsum[st], 0, 0, 0);
      lsum[st] = __builtin_amdgcn_mfma_f32_16x16x32_bf16(ap[st][1], vones, lsum[st], 0, 0, 0);
    }
#pragma unroll
    for (int dt = 0; dt < 4; ++dt) {
      const bf16x8 bv0 = *(const bf16x8*)(vl + off[dt][0]);
      const bf16x8 bv1 = *(const bf16x8*)(vl + off[dt][1]);
#pragma unroll
      for (int st = 0; st < 4; ++st) {
        f32x4 a = accO[st][dt];
        a = __builtin_amdgcn_mfma_f32_16x16x32_bf16(ap[st][0], bv0, a, 0, 0, 0);
        a = __builtin_amdgcn_mfma_f32_16x16x32_bf16(ap[st][1], bv1, a, 0, 0, 0);
        accO[st][dt] = a;
      }
    }
    __builtin_amdgcn_s_setprio(0);
  }

  const int oc0 = (bh & 15) * 64;
#pragma unroll
  for (int st = 0; st < 4; ++st) {
    const int orow0 = (bh >> 4) * 2048 + qb * 256 + w * 64 + st * 16 + lg * 4;
    f32x4 rc;
#pragma unroll
    for (int r = 0; r < 4; ++r) rc[r] = 1.0f / lsum[st][r];
#pragma unroll
    for (int dt = 0; dt < 4; ++dt)
#pragma unroll
      for (int r = 0; r < 4; ++r)
        O[(size_t)(orow0 + r) * 1024 + oc0 + dt * 16 + lr] = f2b(accO[st][dt][r] * rc[r]);
  }
}

// ---------------- launch ----------------
extern "C" void kernel_launch(void* const* d_in, const int* in_sizes, int n_in,
                              void* d_out, int out_size, void* d_ws, size_t ws_size,
                              hipStream_t stream) {
  (void)in_sizes; (void)n_in; (void)out_size; (void)ws_size;
  const float* query = (const float*)d_in[0];
  const float* key_  = (const float*)d_in[1];
  const float* value = (const float*)d_in[2];
  const float* gauss = (const float*)d_in[3];
  const float* ipw   = (const float*)d_in[4];
  const float* ipb   = (const float*)d_in[5];
  const float* opw   = (const float*)d_in[6];
  const float* opb   = (const float*)d_in[7];

  char* ws = (char*)d_ws;
  // bf16 workspace: [W1 3Mi][W2 1Mi][AO 8Mi][Qf 8Mi][Kf 8Mi][Vt 8Mi] elems
  unsigned short* W1  = (unsigned short*)ws;
  unsigned short* W2  = W1 + ((size_t)3 << 20);
  unsigned short* AO  = W1 + ((size_t)4 << 20);
  unsigned short* Qf  = W1 + ((size_t)12 << 20);
  unsigned short* Kf  = Qf + ((size_t)8 << 20);
  unsigned short* Vt  = Kf + ((size_t)8 << 20);
  float*          gtab = (float*)(Vt + ((size_t)8 << 20));      // 32*2048 f32
  float*          btab = gtab + 32 * 2048;                      // 32*2048 f32

  gw_exp_kernel<<<256, 256, 0, stream>>>(gauss, gtab, btab, 32 * 2048);

  // convert weights to bf16: 4Mi elems / (256 thr * 8) = 2048 blocks
  conv_bf16_kernel<<<2048, 256, 0, stream>>>(ipw, opw, W1);

  // in-projection: M=8192 (64 x 128-row tiles), N=3072 (24 x 128), K=1024
  // A = raw f32 q/k/v via global_load_lds; converted at fragment load
  gemm_ip<<<64 * 24, 512, 0, stream>>>(
      query, key_, value, W1, ipb, gtab, Qf, Kf, Vt, 1024, 24);

  // attention
  attn_kernel<<<512, 256, 0, stream>>>(Qf, Kf, Vt, btab, AO);

  // out-projection: M=8192, N=1024 (4 x 256), K=1024, A = AO bf16
  gemm_op<<<64 * 4, 512, 0, stream>>>(
      AO, W2, opb, (float*)d_out, 1024, 1024, 4);
}

// Round 16
// 189.026 us; speedup vs baseline: 1.0500x; 1.0500x over previous
//
#include <hip/hip_runtime.h>
#include <stdint.h>
#include <stddef.h>

// B=4, L=2048, E=1024, H=16, HD=64, BH=64 heads. f32 inputs/outputs.
// score = (q.k/8 + 0.1) * exp(-10*gauss[bh>>1][m]); softmax over m; @v; out-proj.
// Round 16: REVERT to round-12 configuration (best measured: 189.5 us).
// q/k/v f32->bf16 conversion fused into in-proj A-staging (reg-staged);
// conv pre-pass weights-only; 8-phase GEMM; round-9 attention.

typedef __attribute__((ext_vector_type(8))) short bf16x8;
typedef __attribute__((ext_vector_type(4))) float f32x4;

__device__ __forceinline__ unsigned short f2b(float f) {
  unsigned int u = __builtin_bit_cast(unsigned int, f);
  u += 0x7FFFu + ((u >> 16) & 1u);
  return (unsigned short)(u >> 16);
}
__device__ __forceinline__ bf16x8 cvt8(f32x4 a, f32x4 b) {
  bf16x8 r;
#pragma unroll
  for (int i = 0; i < 4; ++i) { r[i] = (short)f2b(a[i]); r[4 + i] = (short)f2b(b[i]); }
  return r;
}
// packed RNE f32->bf16 via HW instruction (T12): 4 instr per 8 values
__device__ __forceinline__ bf16x8 pk8(f32x4 a, f32x4 b) {
  union { bf16x8 v; unsigned int w[4]; } u;
  asm("v_cvt_pk_bf16_f32 %0, %1, %2" : "=v"(u.w[0]) : "v"(a[0]), "v"(a[1]));
  asm("v_cvt_pk_bf16_f32 %0, %1, %2" : "=v"(u.w[1]) : "v"(a[2]), "v"(a[3]));
  asm("v_cvt_pk_bf16_f32 %0, %1, %2" : "=v"(u.w[2]) : "v"(b[0]), "v"(b[1]));
  asm("v_cvt_pk_bf16_f32 %0, %1, %2" : "=v"(u.w[3]) : "v"(b[2]), "v"(b[3]));
  return u.v;
}
__device__ __forceinline__ float fexp2(float x) { return __builtin_amdgcn_exp2f(x); }

#define GLD16(gp, lp) __builtin_amdgcn_global_load_lds( \
  (const __attribute__((address_space(1))) void*)(gp), \
  (__attribute__((address_space(3))) void*)(lp), 16, 0, 0)

// barrier with full compiler fencing (raw s_barrier has no IR memory semantics)
#define FBAR() do { \
  asm volatile("" ::: "memory"); \
  __builtin_amdgcn_sched_barrier(0); \
  __builtin_amdgcn_s_barrier(); \
  __builtin_amdgcn_sched_barrier(0); \
  asm volatile("" ::: "memory"); \
} while (0)

// ---------------- prep: gtab = exp(-10*gauss)*log2e, btab = 0.1*gtab ----------------
__global__ void __launch_bounds__(256) gw_exp_kernel(const float* __restrict__ g,
                                                     float* __restrict__ gtab,
                                                     float* __restrict__ btab, int n) {
  int i = blockIdx.x * 256 + threadIdx.x;
  if (i < n) {
    const float e = __expf(g[i] * -10.0f) * 1.44269504f;
    gtab[i] = e;
    btab[i] = 0.1f * e;
  }
}

// ---------------- prep: f32 -> bf16 conversion of WEIGHTS only ----------------
// dst layout (1Mi-elem segments): ipw [0, 3M) | opw [3M, 4M)
__global__ void __launch_bounds__(256) conv_bf16_kernel(
    const float* __restrict__ w1, const float* __restrict__ w2,
    unsigned short* __restrict__ dst)
{
  const size_t i = ((size_t)blockIdx.x * 256 + threadIdx.x) * 8;   // 8 elems/thread
  const float* s; size_t off;
  if (i < ((size_t)3 << 20)) { s = w1; off = i; }
  else                       { s = w2; off = i - ((size_t)3 << 20); }
  const f32x4 a = *(const f32x4*)(s + off);
  const f32x4 b = *(const f32x4*)(s + off + 4);
  *(bf16x8*)(dst + i) = cvt8(a, b);
}

// ------- 8-phase GEMM: C = A @ B^T (+bias), 128x256 tile, BK=64, 8 waves -------
// Wave (wm=w>>2, wn=w&3) owns 64x64: acc[4][4]. LDS slot s (48KB):
// A tile 128x64 bf16 @ +0 (16KB) | B half0 @ +16K | B half1 @ +32K.
// Rows are 128B (64 bf16); LDS[row][c] holds global chunk c^(row&7).
// EPI==0: A is f32 (q/k/v raw inputs, selected by tn>>2). A staged via regs:
//   4 global_load_dwordx4 -> 4 cvt_pk -> 2 ds_write_b128 (swizzle applied at
//   the global source element offset, LDS dest linear). Per slot: 4 A-regloads
//   + 4 B GLD16 = 8 VMEM. p0/p2 issue 6 new ops then vmcnt(6) retires the 8
//   older (slot-about-to-open's A-regs + B); cvt+ds_write that slot's A;
//   lgkmcnt(0); barrier. Race ledger: slot-s A written in the barrier window
//   after its last read (closed by p1/p3 FBAR) and before its opening barrier;
//   vmcnt counts are phase-group-aligned (order-insensitive within a phase);
//   "memory" asm pins VMEM/DS ops inside their phase. Last iter p2: vmcnt(0).
// EPI==1: A bf16 (AO), original r11 path (2 GLD16, vmcnt(4)).
template<int EPI>
__global__ void __launch_bounds__(512, 2) gemm8p(
    const float* __restrict__ Aq, const float* __restrict__ Ak,
    const float* __restrict__ Av, const unsigned short* __restrict__ Abf,
    const unsigned short* __restrict__ Bw,
    const float* __restrict__ bias, const float* __restrict__ gtab,
    unsigned short* __restrict__ Qo, unsigned short* __restrict__ Ko,
    unsigned short* __restrict__ Vto, float* __restrict__ Co,
    int N, int K, int nTN)
{
  const int nwg = gridDim.x;
  const int cpx = nwg >> 3;                                     // nwg % 8 == 0
  const int bid2 = (blockIdx.x & 7) * cpx + (blockIdx.x >> 3);  // XCD swizzle
  const int tm = bid2 / nTN, tn = bid2 % nTN;   // tm: 128-row tiles, tn: 256-col

  __shared__ __align__(16) char lds[2][49152];

  const int tid = threadIdx.x;
  const int w = tid >> 6, l = tid & 63;
  const int lr = l & 15, lg = l >> 4;
  const int wm = w >> 2, wn = w & 3;            // 2 x 4 wave grid
  const size_t Kz = (size_t)K;

  // staging geometry: unit = 16B of bf16 (8 elems). thread t -> row r0 = t>>3,
  // LDS chunk t&7; source element offset e0 = ((t&7)^(r0&7))*8.
  const int r0 = tid >> 3;
  const int e0 = (((tid & 7) ^ ((tid >> 3) & 7)) << 3);
  const size_t arow0 = (size_t)(tm * 128 + r0);
  const size_t brow0 = (size_t)(tn * 256 + r0);

  // EPI==0: f32 A source (q/k/v by tn>>2)
  const float* Af = (tn >> 2) == 0 ? Aq : ((tn >> 2) == 1 ? Ak : Av);

  f32x4 ar0[4], ar1[4];                          // two reg-staged A sets (slot 0/1)
  auto ldA = [&](f32x4* ar, int k0) {
    const float* pa = Af + arow0 * Kz + k0 + e0;
    const float* pb = Af + (arow0 + 64) * Kz + k0 + e0;
    ar[0] = *(const __attribute__((address_space(1))) f32x4*)pa;
    ar[1] = *(const __attribute__((address_space(1))) f32x4*)(pa + 4);
    ar[2] = *(const __attribute__((address_space(1))) f32x4*)pb;
    ar[3] = *(const __attribute__((address_space(1))) f32x4*)(pb + 4);
  };
  auto wrA = [&](f32x4* ar, int s) {
    *(bf16x8*)&lds[s][tid * 16]        = pk8(ar[0], ar[1]);
    *(bf16x8*)&lds[s][8192 + tid * 16] = pk8(ar[2], ar[3]);
  };
  // EPI==1: bf16 A via global_load_lds
  auto stAbf = [&](int s, int k0) {
    GLD16(Abf + arow0 * Kz + k0 + e0,        &lds[s][tid * 16]);
    GLD16(Abf + (arow0 + 64) * Kz + k0 + e0, &lds[s][8192 + tid * 16]);
  };
  auto stB = [&](int s, int h, int k0) {
    const size_t rb = brow0 + h * 128;
    GLD16(Bw + rb * Kz + k0 + e0,        &lds[s][16384 + h * 16384 + tid * 16]);
    GLD16(Bw + (rb + 64) * Kz + k0 + e0, &lds[s][16384 + h * 16384 + 8192 + tid * 16]);
  };

  // fragment LDS byte offsets (A row ra in [0,128); B row br in [0,256))
  int offA[4][2], offB[4][2];
#pragma unroll
  for (int m = 0; m < 4; ++m) {
    const int ra = wm * 64 + m * 16 + lr;
#pragma unroll
    for (int kk = 0; kk < 2; ++kk)
      offA[m][kk] = ra * 128 + ((((kk << 2) | lg) ^ (ra & 7)) << 4);
  }
#pragma unroll
  for (int n = 0; n < 4; ++n) {
    const int br = wn * 64 + n * 16 + lr;
    const int lrow = br & 127;
#pragma unroll
    for (int kk = 0; kk < 2; ++kk)
      offB[n][kk] = 16384 + (br >> 7) * 16384 + lrow * 128 +
                    ((((kk << 2) | lg) ^ (lrow & 7)) << 4);
  }

  f32x4 acc[4][4];
  const f32x4 zero = {0.f, 0.f, 0.f, 0.f};
#pragma unroll
  for (int i = 0; i < 4; ++i)
#pragma unroll
    for (int j = 0; j < 4; ++j) acc[i][j] = zero;

  bf16x8 af[2][2], bf[4][2];

  auto loadA = [&](const char* Ls, int mh) {
#pragma unroll
    for (int mm = 0; mm < 2; ++mm)
#pragma unroll
      for (int kk = 0; kk < 2; ++kk)
        af[mm][kk] = *(const bf16x8*)(Ls + offA[mh * 2 + mm][kk]);
  };
  auto loadB = [&](const char* Ls) {
#pragma unroll
    for (int n = 0; n < 4; ++n)
#pragma unroll
      for (int kk = 0; kk < 2; ++kk)
        bf[n][kk] = *(const bf16x8*)(Ls + offB[n][kk]);
  };
  auto mfmaq = [&](int mh) {
    asm volatile("s_waitcnt lgkmcnt(0)" ::: "memory");
    __builtin_amdgcn_sched_barrier(0);
    __builtin_amdgcn_s_setprio(1);
#pragma unroll
    for (int mm = 0; mm < 2; ++mm)
#pragma unroll
      for (int n = 0; n < 4; ++n) {
        f32x4 a = acc[mh * 2 + mm][n];
        a = __builtin_amdgcn_mfma_f32_16x16x32_bf16(af[mm][0], bf[n][0], a, 0, 0, 0);
        a = __builtin_amdgcn_mfma_f32_16x16x32_bf16(af[mm][1], bf[n][1], a, 0, 0, 0);
        acc[mh * 2 + mm][n] = a;
      }
    __builtin_amdgcn_s_setprio(0);
  };

  const char* L0 = (const char*)lds[0];
  const char* L1 = (const char*)lds[1];

  // prologue: slot0 <- K-tile 0
  if constexpr (EPI == 0) { ldA(ar0, 0); } else { stAbf(0, 0); }
  stB(0, 0, 0); stB(0, 1, 0);

  const int NI = K / 128;                        // iterations, 2 K-tiles each
  for (int i = 0; i < NI; ++i) {
    const int k1 = i * 128 + 64;
    const int k2 = i * 128 + 128;
    // ---- phase 0: open slot0; stage slot1 A(+Bh0)
    if constexpr (EPI == 0) {
      ldA(ar1, k1); stB(1, 0, k1);
      asm volatile("s_waitcnt vmcnt(6)" ::: "memory");
      wrA(ar0, 0);
      asm volatile("s_waitcnt lgkmcnt(0)" ::: "memory");
    } else {
      stAbf(1, k1); stB(1, 0, k1);
      asm volatile("s_waitcnt vmcnt(4)" ::: "memory");
    }
    FBAR();
    loadA(L0, 0); loadB(L0);
    mfmaq(0);
    FBAR();
    // ---- phase 1: slot0 quadrant mh1; stage S1.Bh1
    stB(1, 1, k1);
    loadA(L0, 1);
    mfmaq(1);
    FBAR();
    // ---- phase 2: open slot1; stage next slot0 A(+Bh0)
    if constexpr (EPI == 0) {
      if (i + 1 < NI) {
        ldA(ar0, k2); stB(0, 0, k2);
        asm volatile("s_waitcnt vmcnt(6)" ::: "memory");
      } else {
        asm volatile("s_waitcnt vmcnt(0)" ::: "memory");
      }
      wrA(ar1, 1);
      asm volatile("s_waitcnt lgkmcnt(0)" ::: "memory");
    } else {
      if (i + 1 < NI) {
        stAbf(0, k2); stB(0, 0, k2);
        asm volatile("s_waitcnt vmcnt(4)" ::: "memory");
      } else {
        asm volatile("s_waitcnt vmcnt(0)" ::: "memory");
      }
    }
    FBAR();
    loadA(L1, 0); loadB(L1);
    mfmaq(0);
    FBAR();
    // ---- phase 3: slot1 quadrant mh1; stage next S0.Bh1
    if (i + 1 < NI) stB(0, 1, k2);
    loadA(L1, 1);
    mfmaq(1);
    FBAR();
  }

  // ---------------- epilogue ----------------
  if (EPI == 0 && (tn >> 2) == 2) {
    // V: transpose through LDS -> coalesced Vt rows (tile: 128 n x 256 cols).
    __syncthreads();                              // staging LDS now dead
    char* T = &lds[0][0];                         // [256 cnl][256B], XOR-swizzled
#pragma unroll
    for (int n = 0; n < 4; ++n) {
      const int cnl = wn * 64 + n * 16 + lr;
      const float bv = bias[tn * 256 + cnl];
      const int sw = (cnl & 7) << 4;
#pragma unroll
      for (int m = 0; m < 4; ++m)
#pragma unroll
        for (int r = 0; r < 4; ++r) {
          const int rml = wm * 64 + m * 16 + lg * 4 + r;
          *(unsigned short*)(T + cnl * 256 + ((rml * 2) ^ sw)) = f2b(acc[m][n][r] + bv);
        }
    }
    __syncthreads();
    const int bbase = (tm >> 4) * 16 + (tn - 8) * 4;   // bh = bbase + (cnl>>6)
    const size_t ncol = (size_t)(tm & 15) * 128;
#pragma unroll
    for (int rep = 0; rep < 8; ++rep) {
      const int U = rep * 512 + tid;              // 4096 units of 16B
      const int row = U >> 4;                     // cnl
      const int un = U & 15;
      const bf16x8 vv = *(const bf16x8*)(T + row * 256 + ((un * 16) ^ ((row & 7) << 4)));
      const int bh = bbase + (row >> 6);
      const int d = row & 63;
      *(bf16x8*)(Vto + ((size_t)bh * 64 + d) * 2048 + ncol + un * 8) = vv;
    }
  } else {
    // q/k (EPI==0) and out-proj (EPI==1): direct stores.
#pragma unroll
    for (int n = 0; n < 4; ++n) {
      const int cn = tn * 256 + wn * 64 + n * 16 + lr;
      const float bv = bias[cn];
      const int j = cn & 1023;
      const float* gK = nullptr;
      if constexpr (EPI == 0) {
        if ((tn >> 2) == 1) {                     // K-block: per-pair g row
          const int bh_ = (tm >> 4) * 16 + (j >> 6);
          gK = gtab + (size_t)(bh_ >> 1) * 2048;
        }
      }
#pragma unroll
      for (int m = 0; m < 4; ++m) {
        const int rm0 = tm * 128 + wm * 64 + m * 16 + lg * 4;
        f32x4 g4;
        if constexpr (EPI == 0) {
          if (gK) g4 = *(const f32x4*)&gK[rm0 & 2047];
        }
#pragma unroll
        for (int r = 0; r < 4; ++r) {
          const int rm = rm0 + r;
          const float val = acc[m][n][r] + bv;
          if constexpr (EPI == 0) {
            const int bh = (rm >> 11) * 16 + (j >> 6);
            const int d = j & 63;
            const int nr = rm & 2047;
            if ((tn >> 2) == 0) Qo[((size_t)bh * 2048 + nr) * 64 + d] = f2b(val * 0.125f);
            else                Ko[((size_t)bh * 2048 + nr) * 64 + d] = f2b(val * g4[r]);
          } else {
            Co[(size_t)rm * N + cn] = val;
          }
        }
      }
    }
  }
}

// ---------------- flash attention: 4 waves x 64 q-rows, 64-key tiles ----------------
// (round 9 — verified)
__global__ void __launch_bounds__(256, 2) attn_kernel(
    const unsigned short* __restrict__ Q, const unsigned short* __restrict__ Kf,
    const unsigned short* __restrict__ Vt, const float* __restrict__ btab,
    unsigned short* __restrict__ O)
{
  const int bid2 = (blockIdx.x & 7) * 64 + (blockIdx.x >> 3);  // grid = 512 = 8*64
  const int bh = bid2 >> 3;
  const int qb = bid2 & 7;
  const int tid = threadIdx.x;
  const int w = tid >> 6, l = tid & 63;
  const int lr = l & 15, lg = l >> 4;

  __shared__ __align__(16) unsigned short Kl[2][64 * 64];
  __shared__ __align__(16) unsigned short Vl[2][64 * 64];

  const int qrow = qb * 256 + w * 64 + lr;
  const unsigned short* qp = &Q[((size_t)bh * 2048 + qrow) * 64];
  bf16x8 aq[4][2];
#pragma unroll
  for (int st = 0; st < 4; ++st) {
    aq[st][0] = *(const bf16x8*)&qp[st * 16 * 64 + lg * 8];
    aq[st][1] = *(const bf16x8*)&qp[st * 16 * 64 + 32 + lg * 8];
  }

  const f32x4 zero = {0.f, 0.f, 0.f, 0.f};
  f32x4 accO[4][4];                               // [st][dt]
  f32x4 lsum[4];
#pragma unroll
  for (int st = 0; st < 4; ++st) {
    lsum[st] = zero;
#pragma unroll
    for (int dt = 0; dt < 4; ++dt) accO[st][dt] = zero;
  }

  const short oneb = (short)0x3F80;               // bf16 1.0
  const bf16x8 vones = {oneb, oneb, oneb, oneb, oneb, oneb, oneb, oneb};

  int off[4][2];
#pragma unroll
  for (int mt = 0; mt < 4; ++mt)
#pragma unroll
    for (int c = 0; c < 2; ++c) {
      const int rr = mt * 16 + lr;
      off[mt][c] = rr * 128 + ((((c << 2) + lg) ^ (rr & 7)) << 4);
    }

  const int rr0 = w * 8 + (l >> 3);
  const int cc = ((l & 7) ^ (rr0 & 7)) * 8;
  const int kk0 = (rr0 & 35) | ((rr0 & 12) << 1) | ((rr0 & 16) >> 2);
  const unsigned short* kSrc = &Kf[((size_t)bh * 2048 + kk0) * 64 + cc];
  const unsigned short* vSrc = &Vt[((size_t)bh * 64 + rr0) * 2048 + cc];

  auto stageKV = [&](int buf) {
    GLD16(kSrc,             &Kl[buf][w * 512]);
    GLD16(kSrc + 32 * 64,   &Kl[buf][(w + 4) * 512]);
    GLD16(vSrc,             &Vl[buf][w * 512]);
    GLD16(vSrc + 32 * 2048, &Vl[buf][(w + 4) * 512]);
    kSrc += 64 * 64;
    vSrc += 64;
  };

  const float* brow = &btab[(size_t)(bh >> 1) * 2048];

  stageKV(0);
  for (int t = 0; t < 32; ++t) {
    __syncthreads();
    if (t + 1 < 32) stageKV((t + 1) & 1);
    const char* kl = (const char*)Kl[t & 1];
    const char* vl = (const char*)Vl[t & 1];

    bf16x8 ap[4][2];
#pragma unroll
    for (int half = 0; half < 2; ++half) {
      f32x4 s[4][2];
      __builtin_amdgcn_s_setprio(1);
#pragma unroll
      for (int mh = 0; mh < 2; ++mh) {
        const int mt = half * 2 + mh;
        const bf16x8 bk0 = *(const bf16x8*)(kl + off[mt][0]);
        const bf16x8 bk1 = *(const bf16x8*)(kl + off[mt][1]);
        const f32x4 b4 = *(const f32x4*)&brow[t * 64 + (half << 5) + (lg << 3) + (mh << 2)];
#pragma unroll
        for (int st = 0; st < 4; ++st) {
          f32x4 a = __builtin_amdgcn_mfma_f32_16x16x32_bf16(bk0, aq[st][0], b4, 0, 0, 0);
          a = __builtin_amdgcn_mfma_f32_16x16x32_bf16(bk1, aq[st][1], a, 0, 0, 0);
          s[st][mh] = a;
        }
      }
      __builtin_amdgcn_s_setprio(0);
#pragma unroll
      for (int st = 0; st < 4; ++st) {
#pragma unroll
        for (int mh = 0; mh < 2; ++mh)
#pragma unroll
          for (int r = 0; r < 4; ++r) s[st][mh][r] = fexp2(s[st][mh][r]);
        ap[st][half] = pk8(s[st][0], s[st][1]);
      }
    }

    __builtin_amdgcn_s_setprio(1);
#pragma unroll
    for (int st = 0; st < 4; ++st) {
      lsum[st] = __builtin_amdgcn_mfma_f32_16x16x32_bf16(ap[st][0], vones, lsum[st], 0, 0, 0);
      lsum[st] = __builtin_amdgcn_mfma_f32_16x16x32_bf16(ap[st][1], vones, lsum[st], 0, 0, 0);
    }
#pragma unroll
    for (int dt = 0; dt < 4; ++dt) {
      const bf16x8 bv0 = *(const bf16x8*)(vl + off[dt][0]);
      const bf16x8 bv1 = *(const bf16x8*)(vl + off[dt][1]);
#pragma unroll
      for (int st = 0; st < 4; ++st) {
        f32x4 a = accO[st][dt];
        a = __builtin_amdgcn_mfma_f32_16x16x32_bf16(ap[st][0], bv0, a, 0, 0, 0);
        a = __builtin_amdgcn_mfma_f32_16x16x32_bf16(ap[st][1], bv1, a, 0, 0, 0);
        accO[st][dt] = a;
      }
    }
    __builtin_amdgcn_s_setprio(0);
  }

  const int oc0 = (bh & 15) * 64;
#pragma unroll
  for (int st = 0; st < 4; ++st) {
    const int orow0 = (bh >> 4) * 2048 + qb * 256 + w * 64 + st * 16 + lg * 4;
    f32x4 rc;
#pragma unroll
    for (int r = 0; r < 4; ++r) rc[r] = 1.0f / lsum[st][r];
#pragma unroll
    for (int dt = 0; dt < 4; ++dt)
#pragma unroll
      for (int r = 0; r < 4; ++r)
        O[(size_t)(orow0 + r) * 1024 + oc0 + dt * 16 + lr] = f2b(accO[st][dt][r] * rc[r]);
  }
}

// ---------------- launch ----------------
extern "C" void kernel_launch(void* const* d_in, const int* in_sizes, int n_in,
                              void* d_out, int out_size, void* d_ws, size_t ws_size,
                              hipStream_t stream) {
  (void)in_sizes; (void)n_in; (void)out_size; (void)ws_size;
  const float* query = (const float*)d_in[0];
  const float* key_  = (const float*)d_in[1];
  const float* value = (const float*)d_in[2];
  const float* gauss = (const float*)d_in[3];
  const float* ipw   = (const float*)d_in[4];
  const float* ipb   = (const float*)d_in[5];
  const float* opw   = (const float*)d_in[6];
  const float* opb   = (const float*)d_in[7];

  char* ws = (char*)d_ws;
  // bf16 workspace: [W1 3Mi][W2 1Mi][AO 8Mi][Qf 8Mi][Kf 8Mi][Vt 8Mi] elems
  unsigned short* W1  = (unsigned short*)ws;
  unsigned short* W2  = W1 + ((size_t)3 << 20);
  unsigned short* AO  = W1 + ((size_t)4 << 20);
  unsigned short* Qf  = W1 + ((size_t)12 << 20);
  unsigned short* Kf  = Qf + ((size_t)8 << 20);
  unsigned short* Vt  = Kf + ((size_t)8 << 20);
  float*          gtab = (float*)(Vt + ((size_t)8 << 20));      // 32*2048 f32
  float*          btab = gtab + 32 * 2048;                      // 32*2048 f32

  gw_exp_kernel<<<256, 256, 0, stream>>>(gauss, gtab, btab, 32 * 2048);

  // convert weights to bf16: 4Mi elems / (256 thr * 8) = 2048 blocks
  conv_bf16_kernel<<<2048, 256, 0, stream>>>(ipw, opw, W1);

  // in-projection: M=8192 (64 x 128-row tiles), N=3072 (12 x 256), K=1024
  // A = raw f32 q/k/v (conversion fused into staging)
  gemm8p<0><<<64 * 12, 512, 0, stream>>>(
      query, key_, value, nullptr, W1, ipb, gtab,
      Qf, Kf, Vt, nullptr, 3072, 1024, 12);

  // attention
  attn_kernel<<<512, 256, 0, stream>>>(Qf, Kf, Vt, btab, AO);

  // out-projection: M=8192, N=1024 (4 x 256), K=1024, A = AO bf16
  gemm8p<1><<<64 * 4, 512, 0, stream>>>(
      nullptr, nullptr, nullptr, AO, W2, opb, nullptr,
      nullptr, nullptr, nullptr, (float*)d_out, 1024, 1024, 4);
}